// Round 8
// baseline (3901.199 us; speedup 1.0000x reference)
//
#include <hip/hip_runtime.h>
#include <stdint.h>

typedef _Float16 f16;
typedef f16 v8h __attribute__((ext_vector_type(8)));
typedef f16 v4h __attribute__((ext_vector_type(4)));
typedef f16 v2h __attribute__((ext_vector_type(2)));
typedef float v4f __attribute__((ext_vector_type(4)));

#define B_   64
#define L_   49
#define ENC_ 2048
#define D_   512
#define V_   10000
#define VP_  10048
#define T_   60
#define TM_  59
#define KS_  8
#define NBLK 256
#define NREL 16
#define SPIN_MAX (1u << 21)

// dynamic-LDS layout for k_loop
#define WOFF  0        // 8 weight tiles (4 kchunks x 2 halves) x 9216 B = 73728
#define SAOFF 73728    // A-staging double buffer: 2 x 9216 = 18432
#define BOFF  92160    // B-phase arrays: 4608 B
#define DSMEM 98304

__device__ __forceinline__ float sigmoidf_(float x) { return 1.f / (1.f + __expf(-x)); }
__device__ __forceinline__ float tanhf_(float x) {
  float e2 = __expf(2.f * x);
  return 1.f - 2.f / (e2 + 1.f);
}

// ---- coherent (sc0 sc1) accessors, 8B-wide where possible ----
__device__ __forceinline__ unsigned long long ld_sc_u64(const void* p) {
  return __hip_atomic_load((const unsigned long long*)p, __ATOMIC_RELAXED, __HIP_MEMORY_SCOPE_SYSTEM);
}
__device__ __forceinline__ void st_sc_u64(void* p, unsigned long long v) {
  __hip_atomic_store((unsigned long long*)p, v, __ATOMIC_RELAXED, __HIP_MEMORY_SCOPE_SYSTEM);
}
__device__ __forceinline__ void st_sc_u32(void* p, unsigned v) {
  __hip_atomic_store((unsigned*)p, v, __ATOMIC_RELAXED, __HIP_MEMORY_SCOPE_SYSTEM);
}
__device__ __forceinline__ float2 bcf2(unsigned long long v) {
  float2 r; r.x = __uint_as_float((unsigned)v); r.y = __uint_as_float((unsigned)(v >> 32)); return r;
}

// ---- fence-free grid barrier with fan-out release (R7-proven) ----
__device__ __forceinline__ void gsync(unsigned* arrive, unsigned* go, unsigned epoch) {
  int tid = threadIdx.x, blk = blockIdx.x;
  __syncthreads();
  if (blk == 0) {
    if (tid > 0) {
      unsigned n = 0;
      while (__hip_atomic_load(&arrive[tid], __ATOMIC_RELAXED, __HIP_MEMORY_SCOPE_SYSTEM) < epoch) {
        __builtin_amdgcn_s_sleep(2);
        if (++n > SPIN_MAX) break;
      }
    }
    __syncthreads();
    if (tid < NREL)
      __hip_atomic_store(&go[tid * 16], epoch, __ATOMIC_RELAXED, __HIP_MEMORY_SCOPE_SYSTEM);
  } else {
    if (tid == 0) {
      __hip_atomic_store(&arrive[blk], epoch, __ATOMIC_RELAXED, __HIP_MEMORY_SCOPE_SYSTEM);
      const unsigned* gs = &go[(blk & 15) * 16];
      unsigned n = 0;
      while (__hip_atomic_load(gs, __ATOMIC_RELAXED, __HIP_MEMORY_SCOPE_SYSTEM) < epoch) {
        __builtin_amdgcn_s_sleep(2);
        if (++n > SPIN_MAX) break;
      }
    }
  }
  asm volatile("" ::: "memory");
  __syncthreads();
}

// ---------------- one-shot f32 -> f16 casts ----------------
struct CastJobs { const float* s[8]; f16* d[8]; int n4[8]; };
__global__ __launch_bounds__(256) void k_cast(CastJobs J) {
  int a = blockIdx.y;
  int i = blockIdx.x * 256 + threadIdx.x;
  if (i >= J.n4[a]) return;
  float4 v = ((const float4*)J.s[a])[i];
  v4h o; o[0] = (f16)v.x; o[1] = (f16)v.y; o[2] = (f16)v.z; o[3] = (f16)v.w;
  ((v4h*)J.d[a])[i] = o;
}

__global__ __launch_bounds__(256) void k_castpad(const float* __restrict__ s,
                                                 f16* __restrict__ d) {
  int r = blockIdx.y;
  int c4 = blockIdx.x * 256 + threadIdx.x;
  if (c4 >= VP_ / 4) return;
  int c = c4 * 4;
  v4h o;
  if (c + 3 < V_) {
    float4 v = *(const float4*)(s + (size_t)r * V_ + c);
    o[0] = (f16)v.x; o[1] = (f16)v.y; o[2] = (f16)v.z; o[3] = (f16)v.w;
  } else {
    #pragma unroll
    for (int j = 0; j < 4; j++)
      o[j] = (c + j < V_) ? (f16)s[(size_t)r * V_ + c + j] : (f16)0.f;
  }
  *(v4h*)(d + (size_t)r * VP_ + c) = o;
}

// ---------------- mean over L (also resets the grid barrier) ----------------
__global__ __launch_bounds__(256) void k_mean(const f16* __restrict__ inh,
                                              f16* __restrict__ meanh,
                                              unsigned* __restrict__ arrive,
                                              unsigned* __restrict__ go) {
  int b = blockIdx.x, tid = threadIdx.x;
  if (b == 0) {
    __hip_atomic_store(&arrive[tid], 0u, __ATOMIC_RELAXED, __HIP_MEMORY_SCOPE_SYSTEM);
    if (tid < NREL)
      __hip_atomic_store(&go[tid * 16], 0u, __ATOMIC_RELAXED, __HIP_MEMORY_SCOPE_SYSTEM);
  }
  for (int e = tid; e < ENC_; e += 256) {
    float s = 0.f;
    for (int l = 0; l < L_; l++) s += (float)inh[((size_t)(b * L_ + l)) * ENC_ + e];
    meanh[b * ENC_ + e] = (f16)(s * (1.f / 49.f));
  }
}

// ---------------- emb gather ----------------
__global__ __launch_bounds__(128) void k_embgather(const int* __restrict__ captions,
    const float* __restrict__ embw, f16* __restrict__ emball) {
  int row = blockIdx.x;
  int t = row >> 6, b = row & 63;
  int cap = captions[b * T_ + t];
  int k = threadIdx.x * 4;
  float4 v = *(const float4*)(embw + (size_t)cap * 512 + k);
  v4h o; o[0] = (f16)v.x; o[1] = (f16)v.y; o[2] = (f16)v.z; o[3] = (f16)v.w;
  *(v4h*)(emball + (size_t)row * 512 + k) = o;
}

// ---------------- shared 64x64 MFMA tile helpers ----------------
struct AR { uint4 x, y; };
struct BR { v4h b[4]; };

__device__ __forceinline__ AR load_a64(const f16* src, int lda, int tid) {
  int r = tid >> 2, k = (tid & 3) << 4;
  const f16* p = src + (size_t)r * lda + k;
  AR a; a.x = *(const uint4*)p; a.y = *(const uint4*)(p + 8); return a;
}
__device__ __forceinline__ AR load_a64_sc(const f16* src, int lda, int tid) {
  int r = tid >> 2, k = (tid & 3) << 4;
  const unsigned long long* p = (const unsigned long long*)(src + (size_t)r * lda + k);
  unsigned long long w0 = ld_sc_u64(p + 0), w1 = ld_sc_u64(p + 1);
  unsigned long long w2 = ld_sc_u64(p + 2), w3 = ld_sc_u64(p + 3);
  AR a;
  a.x.x = (unsigned)w0; a.x.y = (unsigned)(w0 >> 32);
  a.x.z = (unsigned)w1; a.x.w = (unsigned)(w1 >> 32);
  a.y.x = (unsigned)w2; a.y.y = (unsigned)(w2 >> 32);
  a.y.z = (unsigned)w3; a.y.w = (unsigned)(w3 >> 32);
  return a;
}
__device__ __forceinline__ void write_a64(const AR& a, f16 (*sA)[72], int tid) {
  int r = tid >> 2, k = (tid & 3) << 4;
  *(uint4*)&sA[r][k] = a.x; *(uint4*)&sA[r][k + 8] = a.y;
}
__device__ __forceinline__ BR load_b64(const f16* src, int ldb, int tid) {
  BR b;
  #pragma unroll
  for (int s = 0; s < 4; s++) {
    int slot = tid + s * 256;
    int kr = slot >> 4, nc = (slot & 15) << 2;
    b.b[s] = *(const v4h*)(src + (size_t)kr * ldb + nc);
  }
  return b;
}
__device__ __forceinline__ void write_b64(const BR& b, f16 (*sB)[72], int tid) {
  #pragma unroll
  for (int s = 0; s < 4; s++) {
    int slot = tid + s * 256;
    int kr = slot >> 4, nc = (slot & 15) << 2;
    sB[nc + 0][kr] = b.b[s][0]; sB[nc + 1][kr] = b.b[s][1];
    sB[nc + 2][kr] = b.b[s][2]; sB[nc + 3][kr] = b.b[s][3];
  }
}
__device__ __forceinline__ void mfma_tile(const f16 (*sA)[72], const f16 (*sB)[72],
                                          int fr, int fq, int wv, v4f* acc) {
  #pragma unroll
  for (int kk = 0; kk < 64; kk += 32) {
    v8h bfr = *(const v8h*)&sB[wv * 16 + fr][kk + fq * 8];
    #pragma unroll
    for (int mt = 0; mt < 4; mt++) {
      v8h afr = *(const v8h*)&sA[mt * 16 + fr][kk + fq * 8];
      acc[mt] = __builtin_amdgcn_mfma_f32_16x16x32_f16(afr, bfr, acc[mt], 0, 0, 0);
    }
  }
}

// double-buffered K loop (pre/post kernels, static smem)
template <typename F>
__device__ __forceinline__ void gemm_db(int nch, F srcf,
    f16 (*sA)[64][72], f16 (*sB)[64][72],
    int tid, int fr, int fq, int wv, v4f* acc) {
  const f16 *ap, *bp; int la, lb;
  srcf(0, ap, la, bp, lb);
  AR ar = load_a64(ap, la, tid);
  BR br = load_b64(bp, lb, tid);
  int cur = 0;
  for (int ch = 0; ch < nch; ch++) {
    AR an = ar; BR bn = br;
    if (ch + 1 < nch) {
      srcf(ch + 1, ap, la, bp, lb);
      an = load_a64(ap, la, tid);
      bn = load_b64(bp, lb, tid);
    }
    write_a64(ar, sA[cur], tid);
    write_b64(br, sB[cur], tid);
    __syncthreads();
    mfma_tile(sA[cur], sB[cur], fr, fq, wv, acc);
    ar = an; br = bn; cur ^= 1;
  }
}

// k_loop GEMM: A staged from global (sc 8B), B resident in LDS, 128-wide tile
__device__ __forceinline__ void gemm_lds4(const f16* Abase, int lda, char* smem,
    int tid, int fr, int fq, int wv, v4f acc[2][4]) {
  f16 (*sAb)[64][72] = (f16(*)[64][72])(smem + SAOFF);
  AR ar = load_a64_sc(Abase, lda, tid);
  int cur = 0;
  for (int ch = 0; ch < 4; ch++) {
    AR an = ar;
    if (ch + 1 < 4) an = load_a64_sc(Abase + (ch + 1) * 64, lda, tid);
    write_a64(ar, sAb[cur], tid);
    __syncthreads();
    #pragma unroll
    for (int hf = 0; hf < 2; hf++) {
      const f16 (*sBw)[72] = (const f16(*)[72])(smem + (size_t)(ch * 2 + hf) * 9216);
      #pragma unroll
      for (int kk = 0; kk < 64; kk += 32) {
        v8h bfr = *(const v8h*)&sBw[wv * 16 + fr][kk + fq * 8];
        #pragma unroll
        for (int mt = 0; mt < 4; mt++) {
          v8h afr = *(const v8h*)&sAb[cur][mt * 16 + fr][kk + fq * 8];
          acc[hf][mt] = __builtin_amdgcn_mfma_f32_16x16x32_f16(afr, bfr, acc[hf][mt], 0, 0, 0);
        }
      }
    }
    ar = an; cur ^= 1;
  }
}

// ---------------- h0/c0 ----------------
__global__ __launch_bounds__(256) void k_h0c0(const f16* __restrict__ meanh,
    const f16* __restrict__ hw, const float* __restrict__ hb,
    const f16* __restrict__ cw, const float* __restrict__ cb,
    float* __restrict__ h, float* __restrict__ c, f16* __restrict__ hh) {
  __shared__ __align__(16) f16 sA[2][64][72], sB[2][64][72];
  int tid = threadIdx.x, lane = tid & 63, wv = tid >> 6, fr = lane & 15, fq = lane >> 4;
  int n0 = blockIdx.x * 64;
  bool ish = n0 < 512;
  const f16* W = ish ? hw : cw;
  const float* bb = ish ? hb : cb;
  int nb = ish ? n0 : (n0 - 512);
  v4f acc[4] = {};
  auto src = [&](int ch, const f16*& ap, int& la, const f16*& bp, int& lb) {
    ap = meanh + ch * 64; la = ENC_;
    bp = W + (size_t)(ch * 64) * 512 + nb; lb = 512;
  };
  gemm_db(32, src, sA, sB, tid, fr, fq, wv, acc);
  int col = nb + wv * 16 + fr;
  float bv = bb[col];
  #pragma unroll
  for (int mt = 0; mt < 4; mt++)
    #pragma unroll
    for (int r = 0; r < 4; r++) {
      int b = mt * 16 + fq * 4 + r;
      float v = acc[mt][r] + bv;
      if (ish) { h[b * 512 + col] = v; hh[b * 512 + col] = (f16)v; }
      else       c[b * 512 + col] = v;
    }
}

// ---------------- enc_proj (f16 output) ----------------
__global__ __launch_bounds__(256) void k_ep(const f16* __restrict__ inh,
    const f16* __restrict__ Wh, const float* __restrict__ bias,
    f16* __restrict__ out) {
  __shared__ __align__(16) f16 sA[2][64][72], sB[2][64][72];
  int tid = threadIdx.x, lane = tid & 63, wv = tid >> 6, fr = lane & 15, fq = lane >> 4;
  int m0 = blockIdx.x * 64, n0 = blockIdx.y * 64;
  v4f acc[4] = {};
  auto src = [&](int ch, const f16*& ap, int& la, const f16*& bp, int& lb) {
    ap = inh + (size_t)m0 * ENC_ + ch * 64; la = ENC_;
    bp = Wh + (size_t)(ch * 64) * 512 + n0; lb = 512;
  };
  gemm_db(32, src, sA, sB, tid, fr, fq, wv, acc);
  int col = n0 + wv * 16 + fr;
  float bv = bias[col];
  #pragma unroll
  for (int mt = 0; mt < 4; mt++)
    #pragma unroll
    for (int r = 0; r < 4; r++)
      out[(size_t)(m0 + mt * 16 + fq * 4 + r) * 512 + col] = (f16)(acc[mt][r] + bv);
}

// ---------------- embproj ----------------
__global__ __launch_bounds__(256) void k_embproj(const f16* __restrict__ emball,
    const f16* __restrict__ wih, const float* __restrict__ bih,
    const float* __restrict__ bhh, float* __restrict__ out) {
  __shared__ __align__(16) f16 sA[2][64][72], sB[2][64][72];
  int tid = threadIdx.x, lane = tid & 63, wv = tid >> 6, fr = lane & 15, fq = lane >> 4;
  int m0 = blockIdx.x * 64, n0 = blockIdx.y * 64;
  v4f acc[4] = {};
  auto src = [&](int ch, const f16*& ap, int& la, const f16*& bp, int& lb) {
    ap = emball + (size_t)m0 * 512 + ch * 64; la = 512;
    bp = wih + (size_t)(ch * 64) * 2048 + n0; lb = 2048;
  };
  gemm_db(8, src, sA, sB, tid, fr, fq, wv, acc);
  int col = n0 + wv * 16 + fr;
  float bv = bih[col] + bhh[col];
  #pragma unroll
  for (int mt = 0; mt < 4; mt++)
    #pragma unroll
    for (int r = 0; r < 4; r++)
      out[(size_t)(m0 + mt * 16 + fq * 4 + r) * 2048 + col] = acc[mt][r] + bv;
}

// ---------------- persistent time-loop kernel ----------------
struct LP {
  const f16* inh; const f16* encproj; const float* att_w; const float* att_b;
  const f16* daw; const float* bd; const f16* avw; const float* ba;
  const f16* whh; const f16* wih2; const float* embpj; const int* lens;
  float* aout;   // [2][64][4608]
  f16* xg; float* part;   // part [8][64][2048]
  float* h; float* c; f16* hh; f16* hseq; float* probs;
  unsigned* arrive; unsigned* go;
};

__global__ __launch_bounds__(256) void k_loop(LP P) {
  extern __shared__ __align__(16) char smem[];
  int tid = threadIdx.x, lane = tid & 63, wv = tid >> 6;
  int fr = lane & 15, fq = lane >> 4;
  int blk = blockIdx.x;
  unsigned bno = 0;

  bool isA = (blk >= 128 && blk < 200);
  bool isB = (blk < 64);
  bool isC = (blk < 128);
  bool isD = (blk >= 192);

  // D-role state in registers (2 consecutive d per thread)
  float hreg[2] = {0.f, 0.f}, creg[2] = {0.f, 0.f};
  int dbB = 0, dplen = 0;
  if (isD) {
    dbB = blk - 192;
    int d0 = tid * 2;
    hreg[0] = P.h[(size_t)dbB * 512 + d0];     hreg[1] = P.h[(size_t)dbB * 512 + d0 + 1];
    creg[0] = P.c[(size_t)dbB * 512 + d0];     creg[1] = P.c[(size_t)dbB * 512 + d0 + 1];
    dplen = P.lens[dbB] - 1;
  }
  int bplen = isB ? (P.lens[blk] - 1) : 0;

  // ---- prologue: stage this block's weight slice into LDS (once) ----
  int za = 0, n0a = 0;
  if (isA) {
    int nt = blk - 128;
    za = (nt >= 36) ? 1 : 0;
    int tile = nt - za * 36;
    n0a = tile * 128;
    const f16* W; int ldb, bo;
    if (n0a < 512)       { W = P.daw; ldb = 512;  bo = n0a; }
    else if (n0a < 2560) { W = P.avw; ldb = 2048; bo = n0a - 512; }
    else                 { W = P.whh; ldb = 2048; bo = n0a - 2560; }
    for (int ch = 0; ch < 4; ch++)
      #pragma unroll
      for (int hf = 0; hf < 2; hf++) {
        BR tt = load_b64(W + (size_t)(za * 256 + ch * 64) * ldb + bo + hf * 64, ldb, tid);
        write_b64(tt, (f16(*)[72])(smem + (size_t)(ch * 2 + hf) * 9216), tid);
      }
  }
  int zc = 0, n0c = 0;
  if (isC) {
    zc = blk >> 4;
    n0c = (blk & 15) * 128;
    for (int ch = 0; ch < 4; ch++)
      #pragma unroll
      for (int hf = 0; hf < 2; hf++) {
        BR tt = load_b64(P.wih2 + (size_t)(zc * 256 + ch * 64) * 2048 + n0c + hf * 64, 2048, tid);
        write_b64(tt, (f16(*)[72])(smem + (size_t)(ch * 2 + hf) * 9216), tid);
      }
  }
  __syncthreads();

  for (int t = 0; t < TM_; t++) {
    // ---- Phase A: h @ [Wd|Wa|whh], weights in LDS, 128-wide tile ----
    if (isA) {
      v4f acc[2][4] = {};
      gemm_lds4(P.hh + za * 256, 512, smem, tid, fr, fq, wv, acc);
      float* ao = P.aout + (size_t)za * 64 * 4608;
      #pragma unroll
      for (int hf = 0; hf < 2; hf++)
        #pragma unroll
        for (int mt = 0; mt < 4; mt++)
          #pragma unroll
          for (int r = 0; r < 4; r++) {
            int bb = mt * 16 + fq * 4 + r;
            int col = n0a + hf * 64 + wv * 16 + fr;
            float v = acc[hf][mt][r];
            float vp = __shfl_xor(v, 1);
            if (!(fr & 1)) {
              unsigned long long pk = (unsigned long long)__float_as_uint(v)
                                    | ((unsigned long long)__float_as_uint(vp) << 32);
              st_sc_u64(&ao[(size_t)bb * 4608 + col], pk);
            }
          }
    }
    gsync(P.arrive, P.go, ++bno);

    // ---- Phase B: attention + gate + xg (one block per batch) ----
    if (isB) {
      float* sd = (float*)(smem + BOFF);
      float* sw = sd + 512;
      float* ss = sw + 512;
      float* sp = ss + 64;
      int b = blk;
      const float* a0 = P.aout + (size_t)b * 4608;
      const float* a1 = a0 + (size_t)64 * 4608;
      {
        int i0 = tid * 2;
        float2 f0 = bcf2(ld_sc_u64(a0 + i0));
        float2 f1 = bcf2(ld_sc_u64(a1 + i0));
        float2 bd2 = *(const float2*)(P.bd + i0);
        sd[i0] = f0.x + f1.x + bd2.x;
        sd[i0 + 1] = f0.y + f1.y + bd2.y;
        float2 aw = *(const float2*)(P.att_w + i0);
        sw[i0] = aw.x; sw[i0 + 1] = aw.y;
      }
      __syncthreads();
      for (int l = wv; l < L_; l += 4) {
        const f16* ep = P.encproj + ((size_t)(b * L_ + l)) * 512;
        float p = 0.f;
        #pragma unroll
        for (int j = 0; j < 8; j++) {
          int A0 = lane + j * 64;
          float v = (float)ep[A0] + sd[A0];
          p = fmaf(fmaxf(v, 0.f), sw[A0], p);
        }
        #pragma unroll
        for (int off = 32; off > 0; off >>= 1) p += __shfl_xor(p, off);
        if (lane == 0) ss[l] = p;
      }
      __syncthreads();
      if (wv == 0) {
        float e = (lane < L_) ? __expf(ss[lane] + P.att_b[0]) : 0.f;  // scores ~+-0.5: max-free
        float s = e;
        #pragma unroll
        for (int off = 32; off > 0; off >>= 1) s += __shfl_xor(s, off);
        float pr = e / s;
        if (lane < L_) {
          sp[lane] = pr;
          bool act = t < bplen;
          P.probs[((size_t)b * TM_ + t) * L_ + lane] = act ? pr : 0.f;
        }
      }
      __syncthreads();
      int e0 = tid * 8;
      float av[8] = {};
      const f16* ip = P.inh + (size_t)b * L_ * ENC_ + e0;
      for (int l = 0; l < L_; l++) {
        v8h x = *(const v8h*)(ip + (size_t)l * ENC_);
        float pl = sp[l];
        #pragma unroll
        for (int j = 0; j < 8; j++) av[j] = fmaf(pl, (float)x[j], av[j]);
      }
      v8h og;
      #pragma unroll
      for (int jp = 0; jp < 4; jp++) {
        int e = e0 + jp * 2;
        float2 f0 = bcf2(ld_sc_u64(a0 + 512 + e));
        float2 f1 = bcf2(ld_sc_u64(a1 + 512 + e));
        float2 ba2 = *(const float2*)(P.ba + e);
        float ga = sigmoidf_(f0.x + f1.x + ba2.x);
        float gb = sigmoidf_(f0.y + f1.y + ba2.y);
        og[jp * 2] = (f16)(av[jp * 2] * ga);
        og[jp * 2 + 1] = (f16)(av[jp * 2 + 1] * gb);
      }
      unsigned long long px0, px1;
      __builtin_memcpy(&px0, &og, 8);
      __builtin_memcpy(&px1, ((const char*)&og) + 8, 8);
      st_sc_u64(P.xg + (size_t)b * 2048 + e0, px0);
      st_sc_u64(P.xg + (size_t)b * 2048 + e0 + 4, px1);
    }
    gsync(P.arrive, P.go, ++bno);

    // ---- Phase C: xg @ wih2, weights in LDS, 128-wide tile, split-K=8 ----
    if (isC) {
      v4f acc[2][4] = {};
      gemm_lds4(P.xg + zc * 256, 2048, smem, tid, fr, fq, wv, acc);
      float* pp = P.part + (size_t)zc * 64 * 2048;
      #pragma unroll
      for (int hf = 0; hf < 2; hf++)
        #pragma unroll
        for (int mt = 0; mt < 4; mt++)
          #pragma unroll
          for (int r = 0; r < 4; r++) {
            int bb = mt * 16 + fq * 4 + r;
            int col = n0c + hf * 64 + wv * 16 + fr;
            float v = acc[hf][mt][r];
            float vp = __shfl_xor(v, 1);
            if (!(fr & 1)) {
              unsigned long long pk = (unsigned long long)__float_as_uint(v)
                                    | ((unsigned long long)__float_as_uint(vp) << 32);
              st_sc_u64(&pp[(size_t)bb * 2048 + col], pk);
            }
          }
    }
    gsync(P.arrive, P.go, ++bno);

    // ---- Phase D: reduce + LSTM cell (one block per batch, 2 d/thread) ----
    if (isD) {
      int b = dbB;
      int d0 = tid * 2;
      float g[4][2];
      #pragma unroll
      for (int qq = 0; qq < 4; qq++) {
        int n = qq * 512 + d0;
        float2 em = *(const float2*)(P.embpj + ((size_t)(t * 64 + b)) * 2048 + n);
        float2 w0 = bcf2(ld_sc_u64(P.aout + (size_t)b * 4608 + 2560 + n));
        float2 w1 = bcf2(ld_sc_u64(P.aout + (size_t)(64 + b) * 4608 + 2560 + n));
        float sx = em.x + w0.x + w1.x;
        float sy = em.y + w0.y + w1.y;
        #pragma unroll
        for (int z = 0; z < KS_; z++) {
          float2 pz = bcf2(ld_sc_u64(P.part + ((size_t)(z * 64 + b)) * 2048 + n));
          sx += pz.x; sy += pz.y;
        }
        g[qq][0] = sx; g[qq][1] = sy;
      }
      bool act = t < dplen;
      v2h hv;
      #pragma unroll
      for (int u = 0; u < 2; u++) {
        float i_ = sigmoidf_(g[0][u]);
        float f_ = sigmoidf_(g[1][u]);
        float gg = tanhf_(g[2][u]);
        float o_ = sigmoidf_(g[3][u]);
        float cn = f_ * creg[u] + i_ * gg;
        float hn = o_ * tanhf_(cn);
        float ho = act ? hn : hreg[u];
        float co = act ? cn : creg[u];
        hreg[u] = ho; creg[u] = co;
        hv[u] = (f16)ho;
      }
      unsigned hu; __builtin_memcpy(&hu, &hv, 4);
      st_sc_u32(P.hh + (size_t)b * 512 + d0, hu);
      *(v2h*)(P.hseq + ((size_t)t * 64 + b) * 512 + d0) = hv;
    }
    gsync(P.arrive, P.go, ++bno);
  }
}

// ---------------- final: preds = hseq @ fc_w + fc_b ----------------
__global__ __launch_bounds__(256) void k_fc(const f16* __restrict__ hseq,
    const f16* __restrict__ W, const float* __restrict__ bias,
    const int* __restrict__ lens, float* __restrict__ preds) {
  __shared__ __align__(16) f16 sA[2][64][72], sB[2][64][72];
  int tid = threadIdx.x, lane = tid & 63, wv = tid >> 6, fr = lane & 15, fq = lane >> 4;
  int t = blockIdx.x, n0 = blockIdx.y * 64;
  v4f acc[4] = {};
  auto src = [&](int ch, const f16*& ap, int& la, const f16*& bp, int& lb) {
    ap = hseq + ((size_t)t * 64) * 512 + ch * 64; la = 512;
    bp = W + (size_t)(ch * 64) * VP_ + n0; lb = VP_;
  };
  gemm_db(8, src, sA, sB, tid, fr, fq, wv, acc);
  int col = n0 + wv * 16 + fr;
  if (col < V_) {
    float bv = bias[col];
    #pragma unroll
    for (int mt = 0; mt < 4; mt++)
      #pragma unroll
      for (int r = 0; r < 4; r++) {
        int b = mt * 16 + fq * 4 + r;
        bool act = t < (lens[b] - 1);
        preds[((size_t)b * TM_ + t) * (size_t)V_ + col] = act ? (acc[mt][r] + bv) : 0.f;
      }
  }
}

extern "C" void kernel_launch(void* const* d_in, const int* in_sizes, int n_in,
                              void* d_out, int out_size, void* d_ws, size_t ws_size,
                              hipStream_t stream) {
  (void)in_sizes; (void)n_in; (void)out_size; (void)ws_size;
  const float* input     = (const float*)d_in[0];
  const int*   captions  = (const int*)d_in[1];
  const int*   lens      = (const int*)d_in[2];
  const float* embw      = (const float*)d_in[3];
  const float* enc_att_w = (const float*)d_in[4];
  const float* enc_att_b = (const float*)d_in[5];
  const float* dec_att_w = (const float*)d_in[6];
  const float* dec_att_b = (const float*)d_in[7];
  const float* att_w     = (const float*)d_in[8];
  const float* att_b     = (const float*)d_in[9];
  const float* h_w       = (const float*)d_in[10];
  const float* h_b       = (const float*)d_in[11];
  const float* c_w       = (const float*)d_in[12];
  const float* c_b       = (const float*)d_in[13];
  const float* actv_w    = (const float*)d_in[14];
  const float* actv_b    = (const float*)d_in[15];
  const float* wih       = (const float*)d_in[16];
  const float* whh       = (const float*)d_in[17];
  const float* bih       = (const float*)d_in[18];
  const float* bhh       = (const float*)d_in[19];
  const float* fc_w      = (const float*)d_in[20];
  const float* fc_b      = (const float*)d_in[21];

  float* preds = (float*)d_out;
  float* probs = preds + (size_t)B_ * TM_ * V_;

  char* w = (char*)d_ws;
  auto alloc = [&](size_t bytes) -> char* {
    char* p = w; w += (bytes + 255) & ~(size_t)255; return p;
  };
  f16* input_h = (f16*)alloc((size_t)6422528 * 2);
  f16* eaw_h   = (f16*)alloc((size_t)1048576 * 2);
  f16* daw_h   = (f16*)alloc((size_t)262144 * 2);
  f16* avw_h   = (f16*)alloc((size_t)1048576 * 2);
  f16* wih_h   = (f16*)alloc((size_t)5242880 * 2);
  f16* whh_h   = (f16*)alloc((size_t)1048576 * 2);
  f16* hw_h    = (f16*)alloc((size_t)1048576 * 2);
  f16* cw_h    = (f16*)alloc((size_t)1048576 * 2);
  f16* fcw_pad = (f16*)alloc((size_t)512 * VP_ * 2);
  f16* meanh   = (f16*)alloc((size_t)B_ * ENC_ * 2);
  f16* encproj = (f16*)alloc((size_t)3136 * 512 * 2);
  float* hbuf  = (float*)alloc((size_t)B_ * 512 * 4);
  float* cbuf  = (float*)alloc((size_t)B_ * 512 * 4);
  f16*   hh    = (f16*)alloc((size_t)B_ * 512 * 2);
  float* aout  = (float*)alloc((size_t)2 * 64 * 4608 * 4);
  f16*   xg    = (f16*)alloc((size_t)B_ * 2048 * 2);
  float* part  = (float*)alloc((size_t)KS_ * B_ * 2048 * 4);
  f16*   hseq  = (f16*)alloc((size_t)TM_ * B_ * 512 * 2);
  f16*   embal = (f16*)alloc((size_t)TM_ * B_ * 512 * 2);
  float* embpj = (float*)alloc((size_t)TM_ * B_ * 2048 * 4);
  unsigned* barmem = (unsigned*)alloc(4096);
  unsigned* arrive = barmem;            // [256] packed
  unsigned* go     = barmem + 256;      // 16 slots spaced 64B

  CastJobs J;
  J.s[0] = input;     J.d[0] = input_h; J.n4[0] = 6422528 / 4;
  J.s[1] = enc_att_w; J.d[1] = eaw_h;   J.n4[1] = 1048576 / 4;
  J.s[2] = dec_att_w; J.d[2] = daw_h;   J.n4[2] = 262144 / 4;
  J.s[3] = actv_w;    J.d[3] = avw_h;   J.n4[3] = 1048576 / 4;
  J.s[4] = wih;       J.d[4] = wih_h;   J.n4[4] = 5242880 / 4;
  J.s[5] = whh;       J.d[5] = whh_h;   J.n4[5] = 1048576 / 4;
  J.s[6] = h_w;       J.d[6] = hw_h;    J.n4[6] = 1048576 / 4;
  J.s[7] = c_w;       J.d[7] = cw_h;    J.n4[7] = 1048576 / 4;
  k_cast<<<dim3((1605632 + 255) / 256, 8), 256, 0, stream>>>(J);
  k_castpad<<<dim3((VP_ / 4 + 255) / 256, 512), 256, 0, stream>>>(fc_w, fcw_pad);

  k_mean<<<64, 256, 0, stream>>>(input_h, meanh, arrive, go);
  k_embgather<<<TM_ * B_, 128, 0, stream>>>(captions, embw, embal);
  k_h0c0<<<16, 256, 0, stream>>>(meanh, hw_h, h_b, cw_h, c_b, hbuf, cbuf, hh);
  k_ep<<<dim3(49, 8), 256, 0, stream>>>(input_h, eaw_h, enc_att_b, encproj);
  k_embproj<<<dim3(TM_, 32), 256, 0, stream>>>(embal, wih_h, bih, bhh, embpj);

  static bool attr_set = false;
  if (!attr_set) {
    hipFuncSetAttribute((const void*)k_loop,
                        hipFuncAttributeMaxDynamicSharedMemorySize, DSMEM);
    attr_set = true;
  }

  LP P;
  P.inh = input_h; P.encproj = encproj; P.att_w = att_w; P.att_b = att_b;
  P.daw = daw_h; P.bd = dec_att_b; P.avw = avw_h; P.ba = actv_b;
  P.whh = whh_h; P.wih2 = wih_h + (size_t)512 * 2048;
  P.embpj = embpj; P.lens = lens;
  P.aout = aout; P.xg = xg; P.part = part;
  P.h = hbuf; P.c = cbuf; P.hh = hh; P.hseq = hseq; P.probs = probs;
  P.arrive = arrive; P.go = go;
  k_loop<<<NBLK, 256, DSMEM, stream>>>(P);

  k_fc<<<dim3(59, 157), 256, 0, stream>>>(hseq, fcw_pad, fc_b, lens, preds);
}

// Round 9
// 2022.977 us; speedup vs baseline: 1.9284x; 1.9284x over previous
//
#include <hip/hip_runtime.h>
#include <stdint.h>

typedef _Float16 f16;
typedef f16 v8h __attribute__((ext_vector_type(8)));
typedef f16 v4h __attribute__((ext_vector_type(4)));
typedef f16 v2h __attribute__((ext_vector_type(2)));
typedef float v4f __attribute__((ext_vector_type(4)));

#define B_   64
#define L_   49
#define ENC_ 2048
#define D_   512
#define V_   10000
#define VP_  10048
#define T_   60
#define TM_  59
#define KS_  8   // split-K for LSTM gates GEMM

__device__ __forceinline__ float sigmoidf_(float x) { return 1.f / (1.f + __expf(-x)); }
__device__ __forceinline__ float tanhf_(float x) {
  float e2 = __expf(2.f * x);
  return 1.f - 2.f / (e2 + 1.f);
}

// ---------------- one-shot f32 -> f16 casts (8 arrays) ----------------
struct CastJobs { const float* s[8]; f16* d[8]; int n4[8]; };
__global__ __launch_bounds__(256) void k_cast(CastJobs J) {
  int a = blockIdx.y;
  int i = blockIdx.x * 256 + threadIdx.x;
  if (i >= J.n4[a]) return;
  float4 v = ((const float4*)J.s[a])[i];
  v4h o; o[0] = (f16)v.x; o[1] = (f16)v.y; o[2] = (f16)v.z; o[3] = (f16)v.w;
  ((v4h*)J.d[a])[i] = o;
}

// fc_w cast with pad to 10048 columns (zero fill)
__global__ __launch_bounds__(256) void k_castpad(const float* __restrict__ s,
                                                 f16* __restrict__ d) {
  int r = blockIdx.y;
  int c4 = blockIdx.x * 256 + threadIdx.x;
  if (c4 >= VP_ / 4) return;
  int c = c4 * 4;
  v4h o;
  if (c + 3 < V_) {
    float4 v = *(const float4*)(s + (size_t)r * V_ + c);
    o[0] = (f16)v.x; o[1] = (f16)v.y; o[2] = (f16)v.z; o[3] = (f16)v.w;
  } else {
    #pragma unroll
    for (int j = 0; j < 4; j++)
      o[j] = (c + j < V_) ? (f16)s[(size_t)r * V_ + c + j] : (f16)0.f;
  }
  *(v4h*)(d + (size_t)r * VP_ + c) = o;
}

// ---------------- mean over L ----------------
__global__ __launch_bounds__(256) void k_mean(const f16* __restrict__ inh,
                                              f16* __restrict__ meanh) {
  int b = blockIdx.x, tid = threadIdx.x;
  for (int e = tid; e < ENC_; e += 256) {
    float s = 0.f;
    for (int l = 0; l < L_; l++) s += (float)inh[((size_t)(b * L_ + l)) * ENC_ + e];
    meanh[b * ENC_ + e] = (f16)(s * (1.f / 49.f));
  }
}

// ---------------- emb gather (all steps) ----------------
__global__ __launch_bounds__(128) void k_embgather(const int* __restrict__ captions,
    const float* __restrict__ embw, f16* __restrict__ emball) {
  int row = blockIdx.x;           // t*64 + b
  int t = row >> 6, b = row & 63;
  int cap = captions[b * T_ + t];
  int k = threadIdx.x * 4;
  float4 v = *(const float4*)(embw + (size_t)cap * 512 + k);
  v4h o; o[0] = (f16)v.x; o[1] = (f16)v.y; o[2] = (f16)v.z; o[3] = (f16)v.w;
  *(v4h*)(emball + (size_t)row * 512 + k) = o;
}

// ---------------- shared 64x64 f16 MFMA tile helpers ----------------
struct AR { uint4 x, y; };
struct BR { v4h b[4]; };

__device__ __forceinline__ AR load_a64(const f16* src, int lda, int tid) {
  int r = tid >> 2, k = (tid & 3) << 4;
  const f16* p = src + (size_t)r * lda + k;
  AR a; a.x = *(const uint4*)p; a.y = *(const uint4*)(p + 8); return a;
}
__device__ __forceinline__ void write_a64(const AR& a, f16 (*sA)[72], int tid) {
  int r = tid >> 2, k = (tid & 3) << 4;
  *(uint4*)&sA[r][k] = a.x; *(uint4*)&sA[r][k + 8] = a.y;
}
__device__ __forceinline__ BR load_b64(const f16* src, int ldb, int tid) {
  BR b;
  #pragma unroll
  for (int s = 0; s < 4; s++) {
    int slot = tid + s * 256;
    int kr = slot >> 4, nc = (slot & 15) << 2;
    b.b[s] = *(const v4h*)(src + (size_t)kr * ldb + nc);
  }
  return b;
}
__device__ __forceinline__ void write_b64(const BR& b, f16 (*sB)[72], int tid) {
  #pragma unroll
  for (int s = 0; s < 4; s++) {
    int slot = tid + s * 256;
    int kr = slot >> 4, nc = (slot & 15) << 2;
    sB[nc + 0][kr] = b.b[s][0]; sB[nc + 1][kr] = b.b[s][1];
    sB[nc + 2][kr] = b.b[s][2]; sB[nc + 3][kr] = b.b[s][3];
  }
}
__device__ __forceinline__ void mfma_tile(const f16 (*sA)[72], const f16 (*sB)[72],
                                          int fr, int fq, int wv, v4f* acc) {
  #pragma unroll
  for (int kk = 0; kk < 64; kk += 32) {
    v8h bfr = *(const v8h*)&sB[wv * 16 + fr][kk + fq * 8];
    #pragma unroll
    for (int mt = 0; mt < 4; mt++) {
      v8h afr = *(const v8h*)&sA[mt * 16 + fr][kk + fq * 8];
      acc[mt] = __builtin_amdgcn_mfma_f32_16x16x32_f16(afr, bfr, acc[mt], 0, 0, 0);
    }
  }
}

// double-buffered K loop: prefetch chunk ch+1 into regs while MFMA consumes chunk ch.
template <typename F>
__device__ __forceinline__ void gemm_db(int nch, F srcf,
    f16 (*sA)[64][72], f16 (*sB)[64][72],
    int tid, int fr, int fq, int wv, v4f* acc) {
  const f16 *ap, *bp; int la, lb;
  srcf(0, ap, la, bp, lb);
  AR ar = load_a64(ap, la, tid);
  BR br = load_b64(bp, lb, tid);
  int cur = 0;
  for (int ch = 0; ch < nch; ch++) {
    AR an = ar; BR bn = br;
    if (ch + 1 < nch) {
      srcf(ch + 1, ap, la, bp, lb);
      an = load_a64(ap, la, tid);
      bn = load_b64(bp, lb, tid);
    }
    write_a64(ar, sA[cur], tid);
    write_b64(br, sB[cur], tid);
    __syncthreads();
    mfma_tile(sA[cur], sB[cur], fr, fq, wv, acc);
    ar = an; br = bn; cur ^= 1;
  }
}

// ---------------- h0/c0 = mean @ [h_w | c_w] + bias ----------------
__global__ __launch_bounds__(256) void k_h0c0(const f16* __restrict__ meanh,
    const f16* __restrict__ hw, const float* __restrict__ hb,
    const f16* __restrict__ cw, const float* __restrict__ cb,
    float* __restrict__ h, float* __restrict__ c, f16* __restrict__ hh) {
  __shared__ __align__(16) f16 sA[2][64][72], sB[2][64][72];
  int tid = threadIdx.x, lane = tid & 63, wv = tid >> 6, fr = lane & 15, fq = lane >> 4;
  int n0 = blockIdx.x * 64;
  bool ish = n0 < 512;
  const f16* W = ish ? hw : cw;
  const float* bb = ish ? hb : cb;
  int nb = ish ? n0 : (n0 - 512);
  v4f acc[4] = {};
  auto src = [&](int ch, const f16*& ap, int& la, const f16*& bp, int& lb) {
    ap = meanh + ch * 64; la = ENC_;
    bp = W + (size_t)(ch * 64) * 512 + nb; lb = 512;
  };
  gemm_db(32, src, sA, sB, tid, fr, fq, wv, acc);
  int col = nb + wv * 16 + fr;
  float bv = bb[col];
  #pragma unroll
  for (int mt = 0; mt < 4; mt++)
    #pragma unroll
    for (int r = 0; r < 4; r++) {
      int b = mt * 16 + fq * 4 + r;
      float v = acc[mt][r] + bv;
      if (ish) { h[b * 512 + col] = v; hh[b * 512 + col] = (f16)v; }
      else       c[b * 512 + col] = v;
    }
}

// ---------------- enc_proj = input @ enc_att_w + b (f16 out) ----------------
__global__ __launch_bounds__(256) void k_ep(const f16* __restrict__ inh,
    const f16* __restrict__ Wh, const float* __restrict__ bias,
    f16* __restrict__ out) {
  __shared__ __align__(16) f16 sA[2][64][72], sB[2][64][72];
  int tid = threadIdx.x, lane = tid & 63, wv = tid >> 6, fr = lane & 15, fq = lane >> 4;
  int m0 = blockIdx.x * 64, n0 = blockIdx.y * 64;
  v4f acc[4] = {};
  auto src = [&](int ch, const f16*& ap, int& la, const f16*& bp, int& lb) {
    ap = inh + (size_t)m0 * ENC_ + ch * 64; la = ENC_;
    bp = Wh + (size_t)(ch * 64) * 512 + n0; lb = 512;
  };
  gemm_db(32, src, sA, sB, tid, fr, fq, wv, acc);
  int col = n0 + wv * 16 + fr;
  float bv = bias[col];
  #pragma unroll
  for (int mt = 0; mt < 4; mt++)
    #pragma unroll
    for (int r = 0; r < 4; r++)
      out[(size_t)(m0 + mt * 16 + fq * 4 + r) * 512 + col] = (f16)(acc[mt][r] + bv);
}

// ---------------- embproj = emball @ wih[0:512] + bih + bhh ----------------
__global__ __launch_bounds__(256) void k_embproj(const f16* __restrict__ emball,
    const f16* __restrict__ wih, const float* __restrict__ bih,
    const float* __restrict__ bhh, float* __restrict__ out) {
  __shared__ __align__(16) f16 sA[2][64][72], sB[2][64][72];
  int tid = threadIdx.x, lane = tid & 63, wv = tid >> 6, fr = lane & 15, fq = lane >> 4;
  int m0 = blockIdx.x * 64, n0 = blockIdx.y * 64;
  v4f acc[4] = {};
  auto src = [&](int ch, const f16*& ap, int& la, const f16*& bp, int& lb) {
    ap = emball + (size_t)m0 * 512 + ch * 64; la = 512;
    bp = wih + (size_t)(ch * 64) * 2048 + n0; lb = 2048;
  };
  gemm_db(8, src, sA, sB, tid, fr, fq, wv, acc);
  int col = n0 + wv * 16 + fr;
  float bv = bih[col] + bhh[col];
  #pragma unroll
  for (int mt = 0; mt < 4; mt++)
    #pragma unroll
    for (int r = 0; r < 4; r++)
      out[(size_t)(m0 + mt * 16 + fq * 4 + r) * 2048 + col] = acc[mt][r] + bv;
}

// ---------------- per-step: h @ [Wd | Wa | whh], split-K=2, raw partials ----------------
__global__ __launch_bounds__(256) void kA(const f16* __restrict__ hh,
    const f16* __restrict__ Wd, const f16* __restrict__ Wa,
    const f16* __restrict__ Ww, float* __restrict__ aout) {
  __shared__ __align__(16) f16 sA[2][64][72], sB[2][64][72];
  int tid = threadIdx.x, lane = tid & 63, wv = tid >> 6, fr = lane & 15, fq = lane >> 4;
  int n0 = blockIdx.x * 64;
  int z = blockIdx.y;
  const f16* W; int ldb, bo;
  if (n0 < 512)       { W = Wd; ldb = 512;  bo = n0; }
  else if (n0 < 2560) { W = Wa; ldb = 2048; bo = n0 - 512; }
  else                { W = Ww; ldb = 2048; bo = n0 - 2560; }
  v4f acc[4] = {};
  auto src = [&](int ch, const f16*& ap, int& la, const f16*& bp, int& lb) {
    int kl = z * 256 + ch * 64;
    ap = hh + kl; la = 512;
    bp = W + (size_t)kl * ldb + bo; lb = ldb;
  };
  gemm_db(4, src, sA, sB, tid, fr, fq, wv, acc);
  float* ao = aout + (size_t)z * 64 * 4608;
  int col = n0 + wv * 16 + fr;
  #pragma unroll
  for (int mt = 0; mt < 4; mt++)
    #pragma unroll
    for (int r = 0; r < 4; r++) {
      int b = mt * 16 + fq * 4 + r;
      ao[(size_t)b * 4608 + col] = acc[mt][r];
    }
}

// ---------------- per-step: attention + xg staging (512 threads) ----------------
__global__ __launch_bounds__(512) void kB(const f16* __restrict__ inh,
    const f16* __restrict__ encproj, const float* __restrict__ att_w,
    const float* __restrict__ att_b, const float* __restrict__ aout,
    const float* __restrict__ bd, const float* __restrict__ ba,
    const int* __restrict__ lens,
    f16* __restrict__ xg, float* __restrict__ probs, int t) {
  __shared__ float sd[512], sw[512], ss[64], sp[64];
  int b = blockIdx.x, tid = threadIdx.x;
  int lane = tid & 63, wv = tid >> 6;
  const float* a0 = aout + (size_t)b * 4608;
  const float* a1 = a0 + (size_t)64 * 4608;
  sd[tid] = a0[tid] + a1[tid] + bd[tid];
  sw[tid] = att_w[tid];
  __syncthreads();
  for (int l = wv; l < L_; l += 8) {
    const f16* ep = encproj + ((size_t)(b * L_ + l)) * 512;
    float p = 0.f;
    #pragma unroll
    for (int j = 0; j < 8; j++) {
      int a = lane + j * 64;
      float v = (float)ep[a] + sd[a];
      p = fmaf(fmaxf(v, 0.f), sw[a], p);
    }
    #pragma unroll
    for (int off = 32; off > 0; off >>= 1) p += __shfl_xor(p, off);
    if (lane == 0) ss[l] = p;
  }
  __syncthreads();
  if (wv == 0) {
    float v = (lane < L_) ? (ss[lane] + att_b[0]) : -3.0e38f;
    float m = v;
    #pragma unroll
    for (int off = 32; off > 0; off >>= 1) m = fmaxf(m, __shfl_xor(m, off));
    float e = (lane < L_) ? __expf(v - m) : 0.f;
    float s = e;
    #pragma unroll
    for (int off = 32; off > 0; off >>= 1) s += __shfl_xor(s, off);
    float pr = e / s;
    if (lane < L_) {
      sp[lane] = pr;
      bool act = t < (lens[b] - 1);
      probs[((size_t)b * TM_ + t) * L_ + lane] = act ? pr : 0.f;
    }
  }
  __syncthreads();
  int e = tid * 4;
  float av0 = 0, av1 = 0, av2 = 0, av3 = 0;
  const f16* ip = inh + (size_t)b * L_ * ENC_ + e;
  for (int l = 0; l < L_; l++) {
    v4h x = *(const v4h*)(ip + (size_t)l * ENC_);
    float pl = sp[l];
    av0 = fmaf(pl, (float)x[0], av0); av1 = fmaf(pl, (float)x[1], av1);
    av2 = fmaf(pl, (float)x[2], av2); av3 = fmaf(pl, (float)x[3], av3);
  }
  float g0 = sigmoidf_(a0[512 + e]     + a1[512 + e]     + ba[e]);
  float g1 = sigmoidf_(a0[512 + e + 1] + a1[512 + e + 1] + ba[e + 1]);
  float g2 = sigmoidf_(a0[512 + e + 2] + a1[512 + e + 2] + ba[e + 2]);
  float g3 = sigmoidf_(a0[512 + e + 3] + a1[512 + e + 3] + ba[e + 3]);
  v4h o;
  o[0] = (f16)(av0 * g0); o[1] = (f16)(av1 * g1);
  o[2] = (f16)(av2 * g2); o[3] = (f16)(av3 * g3);
  *(v4h*)(xg + (size_t)b * 2048 + e) = o;
}

// ---------------- per-step: xg @ wih[512:2560]  (split-K = 8) ----------------
__global__ __launch_bounds__(256) void kC(const f16* __restrict__ xg,
    const f16* __restrict__ wih, float* __restrict__ part) {
  __shared__ __align__(16) f16 sA[2][64][72], sB[2][64][72];
  int tid = threadIdx.x, lane = tid & 63, wv = tid >> 6, fr = lane & 15, fq = lane >> 4;
  int n0 = blockIdx.x * 64;
  int z = blockIdx.y;
  v4f acc[4] = {};
  auto src = [&](int ch, const f16*& ap, int& la, const f16*& bp, int& lb) {
    int kl = z * 256 + ch * 64;
    ap = xg + kl; la = 2048;
    bp = wih + (size_t)(512 + kl) * 2048 + n0; lb = 2048;
  };
  gemm_db(4, src, sA, sB, tid, fr, fq, wv, acc);
  int col = n0 + wv * 16 + fr;
  float* pp = part + ((size_t)z * 64) * 2048;
  #pragma unroll
  for (int mt = 0; mt < 4; mt++)
    #pragma unroll
    for (int r = 0; r < 4; r++) {
      int b = mt * 16 + fq * 4 + r;
      pp[(size_t)b * 2048 + col] = acc[mt][r];
    }
}

// ---------------- per-step: reduce partials + LSTM cell + state ----------------
__global__ __launch_bounds__(256) void kD(const float* __restrict__ part,
    const float* __restrict__ embproj, const float* __restrict__ aout,
    const int* __restrict__ lens, float* __restrict__ h, float* __restrict__ c,
    f16* __restrict__ hh, f16* __restrict__ hseq, int t) {
  int b = blockIdx.x;
  int d = blockIdx.y * 256 + threadIdx.x;
  const float* a0 = aout + (size_t)b * 4608 + 2560;
  const float* a1 = a0 + (size_t)64 * 4608;
  float g[4];
  #pragma unroll
  for (int q = 0; q < 4; q++) {
    int n = q * 512 + d;
    float s = embproj[((size_t)(t * 64 + b)) * 2048 + n] + a0[n] + a1[n];
    #pragma unroll
    for (int z = 0; z < KS_; z++) s += part[((size_t)(z * 64 + b)) * 2048 + n];
    g[q] = s;
  }
  float i_ = sigmoidf_(g[0]);
  float f_ = sigmoidf_(g[1]);
  float gg = tanhf_(g[2]);
  float o_ = sigmoidf_(g[3]);
  float cold = c[b * 512 + d], hold = h[b * 512 + d];
  float cn = f_ * cold + i_ * gg;
  float hn = o_ * tanhf_(cn);
  bool act = t < (lens[b] - 1);
  float ho = act ? hn : hold;
  float co = act ? cn : cold;
  h[b * 512 + d] = ho;
  c[b * 512 + d] = co;
  hh[b * 512 + d] = (f16)ho;
  hseq[((size_t)t * 64 + b) * 512 + d] = (f16)ho;
}

// ---------------- final: preds = hseq @ fc_w + fc_b (padded W) ----------------
__global__ __launch_bounds__(256) void k_fc(const f16* __restrict__ hseq,
    const f16* __restrict__ W, const float* __restrict__ bias,
    const int* __restrict__ lens, float* __restrict__ preds) {
  __shared__ __align__(16) f16 sA[2][64][72], sB[2][64][72];
  int tid = threadIdx.x, lane = tid & 63, wv = tid >> 6, fr = lane & 15, fq = lane >> 4;
  int t = blockIdx.x, n0 = blockIdx.y * 64;
  v4f acc[4] = {};
  auto src = [&](int ch, const f16*& ap, int& la, const f16*& bp, int& lb) {
    ap = hseq + ((size_t)t * 64) * 512 + ch * 64; la = 512;
    bp = W + (size_t)(ch * 64) * VP_ + n0; lb = VP_;
  };
  gemm_db(8, src, sA, sB, tid, fr, fq, wv, acc);
  int col = n0 + wv * 16 + fr;
  if (col < V_) {
    float bv = bias[col];
    #pragma unroll
    for (int mt = 0; mt < 4; mt++)
      #pragma unroll
      for (int r = 0; r < 4; r++) {
        int b = mt * 16 + fq * 4 + r;
        bool act = t < (lens[b] - 1);
        preds[((size_t)b * TM_ + t) * (size_t)V_ + col] = act ? (acc[mt][r] + bv) : 0.f;
      }
  }
}

extern "C" void kernel_launch(void* const* d_in, const int* in_sizes, int n_in,
                              void* d_out, int out_size, void* d_ws, size_t ws_size,
                              hipStream_t stream) {
  (void)in_sizes; (void)n_in; (void)out_size; (void)ws_size;
  const float* input     = (const float*)d_in[0];
  const int*   captions  = (const int*)d_in[1];
  const int*   lens      = (const int*)d_in[2];
  const float* embw      = (const float*)d_in[3];
  const float* enc_att_w = (const float*)d_in[4];
  const float* enc_att_b = (const float*)d_in[5];
  const float* dec_att_w = (const float*)d_in[6];
  const float* dec_att_b = (const float*)d_in[7];
  const float* att_w     = (const float*)d_in[8];
  const float* att_b     = (const float*)d_in[9];
  const float* h_w       = (const float*)d_in[10];
  const float* h_b       = (const float*)d_in[11];
  const float* c_w       = (const float*)d_in[12];
  const float* c_b       = (const float*)d_in[13];
  const float* actv_w    = (const float*)d_in[14];
  const float* actv_b    = (const float*)d_in[15];
  const float* wih       = (const float*)d_in[16];
  const float* whh       = (const float*)d_in[17];
  const float* bih       = (const float*)d_in[18];
  const float* bhh       = (const float*)d_in[19];
  const float* fc_w      = (const float*)d_in[20];
  const float* fc_b      = (const float*)d_in[21];

  float* preds = (float*)d_out;
  float* probs = preds + (size_t)B_ * TM_ * V_;

  char* w = (char*)d_ws;
  auto alloc = [&](size_t bytes) -> char* {
    char* p = w; w += (bytes + 255) & ~(size_t)255; return p;
  };
  f16* input_h = (f16*)alloc((size_t)6422528 * 2);
  f16* eaw_h   = (f16*)alloc((size_t)1048576 * 2);
  f16* daw_h   = (f16*)alloc((size_t)262144 * 2);
  f16* avw_h   = (f16*)alloc((size_t)1048576 * 2);
  f16* wih_h   = (f16*)alloc((size_t)5242880 * 2);
  f16* whh_h   = (f16*)alloc((size_t)1048576 * 2);
  f16* hw_h    = (f16*)alloc((size_t)1048576 * 2);
  f16* cw_h    = (f16*)alloc((size_t)1048576 * 2);
  f16* fcw_pad = (f16*)alloc((size_t)512 * VP_ * 2);
  f16* meanh   = (f16*)alloc((size_t)B_ * ENC_ * 2);
  f16* encproj = (f16*)alloc((size_t)3136 * 512 * 2);
  float* hbuf  = (float*)alloc((size_t)B_ * 512 * 4);
  float* cbuf  = (float*)alloc((size_t)B_ * 512 * 4);
  f16*   hh    = (f16*)alloc((size_t)B_ * 512 * 2);
  float* aout  = (float*)alloc((size_t)2 * 64 * 4608 * 4);
  f16*   xg    = (f16*)alloc((size_t)B_ * 2048 * 2);
  float* part  = (float*)alloc((size_t)KS_ * B_ * 2048 * 4);
  f16*   hseq  = (f16*)alloc((size_t)TM_ * B_ * 512 * 2);
  f16*   embal = (f16*)alloc((size_t)TM_ * B_ * 512 * 2);
  float* embpj = (float*)alloc((size_t)TM_ * B_ * 2048 * 4);

  CastJobs J;
  J.s[0] = input;     J.d[0] = input_h; J.n4[0] = 6422528 / 4;
  J.s[1] = enc_att_w; J.d[1] = eaw_h;   J.n4[1] = 1048576 / 4;
  J.s[2] = dec_att_w; J.d[2] = daw_h;   J.n4[2] = 262144 / 4;
  J.s[3] = actv_w;    J.d[3] = avw_h;   J.n4[3] = 1048576 / 4;
  J.s[4] = wih;       J.d[4] = wih_h;   J.n4[4] = 5242880 / 4;
  J.s[5] = whh;       J.d[5] = whh_h;   J.n4[5] = 1048576 / 4;
  J.s[6] = h_w;       J.d[6] = hw_h;    J.n4[6] = 1048576 / 4;
  J.s[7] = c_w;       J.d[7] = cw_h;    J.n4[7] = 1048576 / 4;
  k_cast<<<dim3((1605632 + 255) / 256, 8), 256, 0, stream>>>(J);
  k_castpad<<<dim3((VP_ / 4 + 255) / 256, 512), 256, 0, stream>>>(fc_w, fcw_pad);

  k_mean<<<64, 256, 0, stream>>>(input_h, meanh);
  k_embgather<<<TM_ * B_, 128, 0, stream>>>(captions, embw, embal);
  k_h0c0<<<16, 256, 0, stream>>>(meanh, hw_h, h_b, cw_h, c_b, hbuf, cbuf, hh);
  k_ep<<<dim3(49, 8), 256, 0, stream>>>(input_h, eaw_h, enc_att_b, encproj);
  k_embproj<<<dim3(TM_, 32), 256, 0, stream>>>(embal, wih_h, bih, bhh, embpj);

  for (int t = 0; t < TM_; t++) {
    kA<<<dim3(72, 2), 256, 0, stream>>>(hh, daw_h, avw_h, whh_h, aout);
    kB<<<64, 512, 0, stream>>>(input_h, encproj, att_w, att_b, aout,
                               dec_att_b, actv_b, lens, xg, probs, t);
    kC<<<dim3(32, KS_), 256, 0, stream>>>(xg, wih_h, part);
    kD<<<dim3(64, 2), 256, 0, stream>>>(part, embpj, aout, lens, hbuf, cbuf,
                                        hh, hseq, t);
  }
  k_fc<<<dim3(59, 157), 256, 0, stream>>>(hseq, fcw_pad, fc_b, lens, preds);
}